// Round 1
// baseline (2201.208 us; speedup 1.0000x reference)
//
#include <hip/hip_runtime.h>

#define HC 2
#define B 128
#define H1 2048
#define FS2 4096
#define SPL1 2048
#define OC 4
#define SPL2 512
#define NOUT 10
#define T 64
#define BH (B*H1)          // 262144
#define HBH (HC*BH)        // 524288

// ---------------- init: zero all recurrent state ----------------
__global__ __launch_bounds__(256) void init_state(float* __restrict__ ws, int n) {
  int i = blockIdx.x * 256 + threadIdx.x;
  if (i < n) ws[i] = 0.f;
}

// ---------------- batched hidden GEMM: cur[c][r][o] = sum_k x[r][c*2048+k] * w[c][k][o]
// A: rows r in [0,M), row stride FS2, channel offset c*SPL1. B: w_hidden[c] (K=2048 x N=2048).
// 128x128 tile, 256 threads, 8x8 per thread, BK=16.
__global__ __launch_bounds__(256) void gemm_hidden(
    const float* __restrict__ x, const float* __restrict__ w,
    float* __restrict__ cur, int M) {
  const int c = blockIdx.z;
  const float* A  = x + (size_t)c * SPL1;
  const float* Bw = w + (size_t)c * SPL1 * H1;
  float* C = cur + (size_t)c * (size_t)M * H1;

  const int bn = blockIdx.x * 128;
  const int bm = blockIdx.y * 128;

  __shared__ float As[16][132];
  __shared__ float Bs[16][132];

  const int tid = threadIdx.x;
  const int tx = tid & 15;     // n-quadrant
  const int ty = tid >> 4;     // m-quadrant

  const int arow = tid >> 1;        // 0..127
  const int akk  = (tid & 1) * 8;   // 0 or 8
  const int brow = tid >> 4;        // 0..15
  const int bnn  = (tid & 15) * 8;  // 0..120

  float acc[8][8];
  #pragma unroll
  for (int i = 0; i < 8; ++i)
    #pragma unroll
    for (int j = 0; j < 8; ++j) acc[i][j] = 0.f;

  const float* Aptr = A + (size_t)(bm + arow) * FS2;
  const float* Bptr = Bw + (size_t)brow * H1 + bn + bnn;

  for (int k0 = 0; k0 < SPL1; k0 += 16) {
    float4 a0 = *(const float4*)(Aptr + k0 + akk);
    float4 a1 = *(const float4*)(Aptr + k0 + akk + 4);
    float4 b0 = *(const float4*)(Bptr + (size_t)k0 * H1);
    float4 b1 = *(const float4*)(Bptr + (size_t)k0 * H1 + 4);
    __syncthreads();   // previous iteration's LDS reads done
    As[akk+0][arow] = a0.x; As[akk+1][arow] = a0.y;
    As[akk+2][arow] = a0.z; As[akk+3][arow] = a0.w;
    As[akk+4][arow] = a1.x; As[akk+5][arow] = a1.y;
    As[akk+6][arow] = a1.z; As[akk+7][arow] = a1.w;
    *(float4*)&Bs[brow][bnn]     = b0;
    *(float4*)&Bs[brow][bnn + 4] = b1;
    __syncthreads();
    #pragma unroll
    for (int k = 0; k < 16; ++k) {
      float a[8], b[8];
      *(float4*)(a)     = *(const float4*)&As[k][ty*4];
      *(float4*)(a + 4) = *(const float4*)&As[k][64 + ty*4];
      *(float4*)(b)     = *(const float4*)&Bs[k][tx*4];
      *(float4*)(b + 4) = *(const float4*)&Bs[k][64 + tx*4];
      #pragma unroll
      for (int i = 0; i < 8; ++i)
        #pragma unroll
        for (int j = 0; j < 8; ++j)
          acc[i][j] += a[i] * b[j];
    }
  }

  #pragma unroll
  for (int i = 0; i < 8; ++i) {
    int r = bm + ((i < 4) ? (ty*4 + i) : (64 + ty*4 + (i - 4)));
    float4 v0 = make_float4(acc[i][0], acc[i][1], acc[i][2], acc[i][3]);
    float4 v1 = make_float4(acc[i][4], acc[i][5], acc[i][6], acc[i][7]);
    *(float4*)(C + (size_t)r * H1 + bn + tx*4)      = v0;
    *(float4*)(C + (size_t)r * H1 + bn + 64 + tx*4) = v1;
  }
}

// ---------------- per-timestep hidden dynamics (dendritic x2 + somatic) ----------------
__global__ __launch_bounds__(256) void hidden_step(
    const float* __restrict__ cur, size_t cstride,
    float* __restrict__ vdh, float* __restrict__ idh,
    float* __restrict__ vsh, float* __restrict__ ish,
    float* __restrict__ zs) {
  int n = blockIdx.x * 256 + threadIdx.x;
  float ssum = 0.f;
  #pragma unroll
  for (int c = 0; c < HC; ++c) {
    float v   = vdh[c*BH + n];
    float i   = idh[c*BH + n];
    float inp = cur[c*cstride + n];
    float vd = v + 0.1f * (i - v);       // v + dt*tau_mem_inv*((0-v)+i)
    float id = i * 0.8f;                 // i * (1 - dt*tau_syn_inv)
    bool  zb = (vd - 1.0f) > 0.f;        // heaviside(v_dec - v_th)
    vdh[c*BH + n] = zb ? 0.f : vd;       // (1-z)*v_dec + z*0
    idh[c*BH + n] = id + inp;
    ssum += zb ? 1.f : 0.f;
  }
  float v = vsh[n], i = ish[n];
  float vd = v + 0.1f * (i - v);
  float id = i * 0.8f;
  bool  zb = (vd - 1.0f) > 0.f;
  vsh[n] = zb ? 0.f : vd;
  ish[n] = id + ssum;
  zs[n]  = zb ? 1.f : 0.f;
}

// ---------------- per-timestep output layer + readout ----------------
// one block per batch element b
__global__ __launch_bounds__(256) void out_step(
    const float* __restrict__ zs, const float* __restrict__ wout,
    float* __restrict__ vdo, float* __restrict__ ido,
    float* __restrict__ vso, float* __restrict__ iso,
    float* __restrict__ outt) {
  const int b = blockIdx.x;
  __shared__ float zrow[H1];
  __shared__ float co[OC*NOUT];
  __shared__ float sp[OC*NOUT];
  const int tid = threadIdx.x;
  {
    const float4* src = (const float4*)(zs + (size_t)b * H1);
    float4* dst = (float4*)zrow;
    dst[tid]       = src[tid];
    dst[tid + 256] = src[tid + 256];
  }
  __syncthreads();
  const int wave = tid >> 6;   // == oc (4 waves, 4 output channels)
  const int lane = tid & 63;
  for (int o = 0; o < NOUT; ++o) {
    float s = 0.f;
    const float* wcol = wout + (size_t)(wave * SPL2) * NOUT + o;
    #pragma unroll
    for (int it = 0; it < SPL2/64; ++it) {
      int i2 = lane + it*64;
      s += zrow[wave*SPL2 + i2] * wcol[(size_t)i2 * NOUT];
    }
    #pragma unroll
    for (int off = 32; off; off >>= 1) s += __shfl_down(s, off);
    if (lane == 0) co[wave*NOUT + o] = s;
  }
  __syncthreads();
  if (tid < OC*NOUT) {
    int oc = tid / NOUT, o = tid % NOUT;
    int idx = (oc*B + b)*NOUT + o;
    float v = vdo[idx], i = ido[idx];
    float vd = v + 0.1f * (i - v);
    float id = i * 0.8f;
    bool  zb = (vd - 1.0f) > 0.f;
    vdo[idx] = zb ? 0.f : vd;
    ido[idx] = id + co[tid];
    sp[tid] = zb ? 1.f : 0.f;
  }
  __syncthreads();
  if (tid < NOUT) {
    float ssum = ((sp[tid] + sp[NOUT + tid]) + sp[2*NOUT + tid]) + sp[3*NOUT + tid];
    int idx = b*NOUT + tid;
    float v = vso[idx], i = iso[idx];
    float vn = v + 0.1f * (i - v);     // li_step uses old i
    vso[idx] = vn;
    iso[idx] = i * 0.8f + ssum;
    outt[idx] = vn;
  }
}

extern "C" void kernel_launch(void* const* d_in, const int* in_sizes, int n_in,
                              void* d_out, int out_size, void* d_ws, size_t ws_size,
                              hipStream_t stream) {
  const float* x  = (const float*)d_in[0];
  const float* wh = (const float*)d_in[1];
  const float* wo = (const float*)d_in[2];
  float* out = (float*)d_out;
  float* ws  = (float*)d_ws;

  float* vdh = ws;
  float* idh = vdh + HBH;
  float* vsh = idh + HBH;
  float* ish = vsh + BH;
  float* zs  = ish + BH;
  float* vdo = zs  + BH;
  float* ido = vdo + OC*B*NOUT;
  float* vso = ido + OC*B*NOUT;
  float* iso = vso + B*NOUT;
  float* curbuf = iso + B*NOUT;
  const size_t STATE = (size_t)(curbuf - ws);   // 1,847,808 floats

  // time-chunk the current buffer to fit ws (deterministic given ws_size)
  size_t avail = (ws_size/4 > STATE) ? (ws_size/4 - STATE) : 0;
  int Tc = (int)(avail / (size_t)HBH);
  if (Tc > T) Tc = T;
  if (Tc < 1) Tc = 1;

  {
    int n = (int)STATE;
    init_state<<<(n + 255)/256, 256, 0, stream>>>(ws, n);
  }

  for (int t0 = 0; t0 < T; t0 += Tc) {
    int tc = (T - t0 < Tc) ? (T - t0) : Tc;
    int M = tc * B;
    dim3 g(H1/128, M/128, HC);
    gemm_hidden<<<g, 256, 0, stream>>>(x + (size_t)t0 * B * FS2, wh, curbuf, M);
    for (int t = t0; t < t0 + tc; ++t) {
      int tr = t - t0;
      hidden_step<<<BH/256, 256, 0, stream>>>(
          curbuf + (size_t)tr * BH, (size_t)M * H1, vdh, idh, vsh, ish, zs);
      out_step<<<B, 256, 0, stream>>>(
          zs, wo, vdo, ido, vso, iso, out + (size_t)t * B * NOUT);
    }
  }
}

// Round 2
// 548.134 us; speedup vs baseline: 4.0158x; 4.0158x over previous
//
#include <hip/hip_runtime.h>

#define B 128
#define HC 2
#define H1 2048
#define FS2 4096
#define NK 2048
#define OC 4
#define SPL2 512
#define NOUT 10
#define T 64

typedef __attribute__((ext_vector_type(8))) short bf16x8;
typedef __attribute__((ext_vector_type(4))) float f32x4;

__device__ __forceinline__ unsigned short f2bf(float f) {
  unsigned u = __float_as_uint(f);
  u += 0x7fff + ((u >> 16) & 1);   // RNE
  return (unsigned short)(u >> 16);
}
__device__ __forceinline__ float bf2f(unsigned short s) {
  return __uint_as_float(((unsigned)s) << 16);
}

__device__ __forceinline__ void gload16(const void* g, void* l) {
  __builtin_amdgcn_global_load_lds(
      (const __attribute__((address_space(1))) unsigned int*)g,
      (__attribute__((address_space(3))) unsigned int*)l, 16, 0, 0);
}

__global__ __launch_bounds__(256) void init_state(float* __restrict__ p, int n) {
  int i = blockIdx.x * 256 + threadIdx.x;
  if (i < n) p[i] = 0.f;
}

// x fp32 -> hi/lo bf16 (flat, chunk of Mc rows x 4096)
__global__ __launch_bounds__(256) void conv_x(
    const float4* __restrict__ xin, ushort4* __restrict__ xh,
    ushort4* __restrict__ xl, int n4) {
  for (int i = blockIdx.x * 256 + threadIdx.x; i < n4; i += gridDim.x * 256) {
    float4 v = xin[i];
    ushort4 h, lo;
    h.x = f2bf(v.x); h.y = f2bf(v.y); h.z = f2bf(v.z); h.w = f2bf(v.w);
    lo.x = f2bf(v.x - bf2f(h.x)); lo.y = f2bf(v.y - bf2f(h.y));
    lo.z = f2bf(v.z - bf2f(h.z)); lo.w = f2bf(v.w - bf2f(h.w));
    xh[i] = h; xl[i] = lo;
  }
}

// w_hidden [HC][K][N] fp32 -> wt hi/lo [HC][N][K] bf16 (transpose)
__global__ __launch_bounds__(256) void conv_w(
    const float* __restrict__ w, unsigned short* __restrict__ wth,
    unsigned short* __restrict__ wtl) {
  __shared__ float s[64][65];
  const int c = blockIdx.z;
  const int n0 = blockIdx.x * 64, k0 = blockIdx.y * 64;
  const int tid = threadIdx.x;
  const int r = tid >> 4, c4 = (tid & 15) * 4;
#pragma unroll
  for (int q = 0; q < 4; ++q) {
    int kr = r + q * 16;
    float4 v = *(const float4*)(w + ((size_t)c * NK + k0 + kr) * H1 + n0 + c4);
    s[kr][c4 + 0] = v.x; s[kr][c4 + 1] = v.y;
    s[kr][c4 + 2] = v.z; s[kr][c4 + 3] = v.w;
  }
  __syncthreads();
#pragma unroll
  for (int q = 0; q < 4; ++q) {
    int nr = r + q * 16;
    float a0 = s[c4 + 0][nr], a1 = s[c4 + 1][nr];
    float a2 = s[c4 + 2][nr], a3 = s[c4 + 3][nr];
    ushort4 h, lo;
    h.x = f2bf(a0); h.y = f2bf(a1); h.z = f2bf(a2); h.w = f2bf(a3);
    lo.x = f2bf(a0 - bf2f(h.x)); lo.y = f2bf(a1 - bf2f(h.y));
    lo.z = f2bf(a2 - bf2f(h.z)); lo.w = f2bf(a3 - bf2f(h.w));
    size_t off = ((size_t)c * H1 + n0 + nr) * NK + k0 + c4;
    *(ushort4*)(wth + off) = h;
    *(ushort4*)(wtl + off) = lo;
  }
}

// split-bf16 GEMM: cur[c][m][n] = sum_k x[m][c*2048+k]*w[c][k][n], 3-term split
// A tiles from xh/xl [Mc][4096]; B tiles from wth/wtl [HC][N][K] (k-contiguous)
__global__ __launch_bounds__(256) void gemm_split(
    const unsigned short* __restrict__ xh, const unsigned short* __restrict__ xl,
    const unsigned short* __restrict__ wth, const unsigned short* __restrict__ wtl,
    float* __restrict__ cur, int Mc) {
  const int c  = blockIdx.z;
  const int bn = blockIdx.x * 128;
  const int bm = blockIdx.y * 128;
  __shared__ unsigned short lds[16384];  // Ah@0 Al@4096 Bh@8192 Bl@12288 (elements)
  const int tid = threadIdx.x;

  // staging maps: idx=q*256+tid -> (row, phys slot); source pre-swizzled so
  // LDS stays linear for global_load_lds (guide m173 pattern)
  size_t srcA[2], srcB[2];
  unsigned dstOff[2];
#pragma unroll
  for (int q = 0; q < 2; ++q) {
    int idx = q * 256 + tid;
    int row = idx >> 2, ps = idx & 3;
    int ks = (ps - (row >> 1)) & 3;  // logical k-slot stored at this phys slot
    srcA[q] = (size_t)(bm + row) * FS2 + (size_t)c * NK + ks * 8;
    srcB[q] = (size_t)c * NK * H1 + (size_t)(bn + row) * NK + ks * 8;
    dstOff[q] = idx * 8;
  }

  const int l  = tid & 63;
  const int w  = tid >> 6;
  const int wr = w >> 1, wc = w & 1;
  const int lrow = l & 15, lks = l >> 4;
  unsigned aoff[4], boff[4];
#pragma unroll
  for (int m = 0; m < 4; ++m) {
    int row = wr * 64 + m * 16 + lrow;
    int ps = (lks + (row >> 1)) & 3;
    aoff[m] = row * 32 + ps * 8;
    int rn = wc * 64 + m * 16 + lrow;
    int psn = (lks + (rn >> 1)) & 3;
    boff[m] = 8192 + rn * 32 + psn * 8;
  }

  f32x4 acc[4][4];
#pragma unroll
  for (int m = 0; m < 4; ++m)
#pragma unroll
    for (int n = 0; n < 4; ++n) acc[m][n] = (f32x4){0.f, 0.f, 0.f, 0.f};

  for (int k0 = 0; k0 < NK; k0 += 32) {
#pragma unroll
    for (int q = 0; q < 2; ++q) {
      gload16(xh + srcA[q] + k0, &lds[dstOff[q]]);
      gload16(xl + srcA[q] + k0, &lds[4096 + dstOff[q]]);
      gload16(wth + srcB[q] + k0, &lds[8192 + dstOff[q]]);
      gload16(wtl + srcB[q] + k0, &lds[12288 + dstOff[q]]);
    }
    __syncthreads();
    bf16x8 ah[4], al[4], bh[4], bl[4];
#pragma unroll
    for (int m = 0; m < 4; ++m) {
      ah[m] = *(const bf16x8*)&lds[aoff[m]];
      al[m] = *(const bf16x8*)&lds[4096 + aoff[m]];
      bh[m] = *(const bf16x8*)&lds[boff[m]];
      bl[m] = *(const bf16x8*)&lds[4096 + boff[m]];
    }
#pragma unroll
    for (int m = 0; m < 4; ++m)
#pragma unroll
      for (int n = 0; n < 4; ++n) {
        acc[m][n] = __builtin_amdgcn_mfma_f32_16x16x32_bf16(ah[m], bh[n], acc[m][n], 0, 0, 0);
        acc[m][n] = __builtin_amdgcn_mfma_f32_16x16x32_bf16(ah[m], bl[n], acc[m][n], 0, 0, 0);
        acc[m][n] = __builtin_amdgcn_mfma_f32_16x16x32_bf16(al[m], bh[n], acc[m][n], 0, 0, 0);
      }
    __syncthreads();
  }

  float* Cc = cur + (size_t)c * Mc * H1;
#pragma unroll
  for (int m = 0; m < 4; ++m) {
    int grow = bm + wr * 64 + m * 16 + (l >> 4) * 4;
#pragma unroll
    for (int n = 0; n < 4; ++n) {
      int gcol = bn + wc * 64 + n * 16 + (l & 15);
      float* Cp = Cc + (size_t)grow * H1 + gcol;
      Cp[0]        = acc[m][n][0];
      Cp[H1]       = acc[m][n][1];
      Cp[2 * H1]   = acc[m][n][2];
      Cp[3 * H1]   = acc[m][n][3];
    }
  }
}

// fused sequential dynamics: one block per batch row, loops tc timesteps
__global__ __launch_bounds__(1024) void seq_chunk(
    const float* __restrict__ cur, const float* __restrict__ wout,
    float* __restrict__ vdh, float* __restrict__ idh,
    float* __restrict__ vsh, float* __restrict__ ish,
    float* __restrict__ vdo, float* __restrict__ ido,
    float* __restrict__ vso, float* __restrict__ iso,
    float* __restrict__ out, int t0, int tc, int Mc) {
  const int b = blockIdx.x;
  const int tid = threadIdx.x;
  __shared__ float wols[OC * SPL2 * NOUT];  // 80 KB
  __shared__ float curls[HC * H1];
  __shared__ float zls[H1];
  __shared__ float cols[OC * NOUT];
  __shared__ float sp[OC * NOUT];

#pragma unroll
  for (int q = 0; q < 5; ++q) {
    int i4 = q * 1024 + tid;
    ((float4*)wols)[i4] = ((const float4*)wout)[i4];
  }
  float vd[HC][2], id_[HC][2], vs[2], is_[2];
#pragma unroll
  for (int c = 0; c < HC; ++c)
#pragma unroll
    for (int u = 0; u < 2; ++u) {
      size_t o = ((size_t)c * B + b) * H1 + tid + u * 1024;
      vd[c][u] = vdh[o]; id_[c][u] = idh[o];
    }
#pragma unroll
  for (int u = 0; u < 2; ++u) {
    size_t o = (size_t)b * H1 + tid + u * 1024;
    vs[u] = vsh[o]; is_[u] = ish[o];
  }
  float vo = 0.f, io = 0.f, vr = 0.f, ir = 0.f;
  if (tid < OC * NOUT) { vo = vdo[b * OC * NOUT + tid]; io = ido[b * OC * NOUT + tid]; }
  if (tid < NOUT)      { vr = vso[b * NOUT + tid];      ir = iso[b * NOUT + tid]; }

  const int cc = tid >> 9;
  const int h4 = (tid & 511) << 2;
  float4 pf = *(const float4*)(cur + (size_t)cc * Mc * H1 + (size_t)b * H1 + h4);

  for (int tl = 0; tl < tc; ++tl) {
    *(float4*)&curls[cc * H1 + h4] = pf;
    if (tl + 1 < tc)
      pf = *(const float4*)(cur + (size_t)cc * Mc * H1 +
                            (size_t)((tl + 1) * B + b) * H1 + h4);
    __syncthreads();
#pragma unroll
    for (int u = 0; u < 2; ++u) {
      float zsum = 0.f;
#pragma unroll
      for (int c = 0; c < HC; ++c) {
        float v = vd[c][u], i = id_[c][u];
        float vdec = v + 0.1f * (i - v);
        float idec = 0.8f * i;
        bool z = (vdec - 1.0f) > 0.f;
        vd[c][u] = z ? 0.f : vdec;
        id_[c][u] = idec + curls[c * H1 + tid + u * 1024];
        zsum += z ? 1.f : 0.f;
      }
      float v = vs[u], i = is_[u];
      float vdec = v + 0.1f * (i - v);
      float idec = 0.8f * i;
      bool z = (vdec - 1.0f) > 0.f;
      vs[u] = z ? 0.f : vdec;
      is_[u] = idec + zsum;
      zls[tid + u * 1024] = z ? 1.f : 0.f;
    }
    __syncthreads();
    if (tid < 640) {
      int g = tid >> 4, li = tid & 15;
      int oc = g / NOUT, o = g - oc * NOUT;
      float s = 0.f;
#pragma unroll
      for (int j = 0; j < 32; ++j) {
        int i = li + 16 * j;
        s += zls[oc * SPL2 + i] * wols[(oc * SPL2 + i) * NOUT + o];
      }
      s += __shfl_xor(s, 1); s += __shfl_xor(s, 2);
      s += __shfl_xor(s, 4); s += __shfl_xor(s, 8);
      if (li == 0) cols[g] = s;
    }
    __syncthreads();
    if (tid < OC * NOUT) {
      float vdec = vo + 0.1f * (io - vo);
      float idec = 0.8f * io;
      bool z = (vdec - 1.0f) > 0.f;
      vo = z ? 0.f : vdec;
      io = idec + cols[tid];
      sp[tid] = z ? 1.f : 0.f;
    }
    __syncthreads();
    if (tid < NOUT) {
      float ssum = ((sp[tid] + sp[NOUT + tid]) + sp[2 * NOUT + tid]) + sp[3 * NOUT + tid];
      float vn = vr + 0.1f * (ir - vr);
      ir = 0.8f * ir + ssum;
      vr = vn;
      out[((size_t)(t0 + tl) * B + b) * NOUT + tid] = vn;
    }
  }

#pragma unroll
  for (int c = 0; c < HC; ++c)
#pragma unroll
    for (int u = 0; u < 2; ++u) {
      size_t o = ((size_t)c * B + b) * H1 + tid + u * 1024;
      vdh[o] = vd[c][u]; idh[o] = id_[c][u];
    }
#pragma unroll
  for (int u = 0; u < 2; ++u) {
    size_t o = (size_t)b * H1 + tid + u * 1024;
    vsh[o] = vs[u]; ish[o] = is_[u];
  }
  if (tid < OC * NOUT) { vdo[b * OC * NOUT + tid] = vo; ido[b * OC * NOUT + tid] = io; }
  if (tid < NOUT)      { vso[b * NOUT + tid] = vr;      iso[b * NOUT + tid] = ir; }
}

extern "C" void kernel_launch(void* const* d_in, const int* in_sizes, int n_in,
                              void* d_out, int out_size, void* d_ws, size_t ws_size,
                              hipStream_t stream) {
  const float* x  = (const float*)d_in[0];
  const float* wh = (const float*)d_in[1];
  const float* wo = (const float*)d_in[2];
  float* out = (float*)d_out;
  char* ws = (char*)d_ws;

  unsigned short* wth = (unsigned short*)ws;                       // 16 MB
  unsigned short* wtl = wth + (size_t)HC * NK * H1;                // 16 MB
  float* st = (float*)(ws + (size_t)2 * HC * NK * H1 * 2);         // states
  float* vdh = st;
  float* idh = vdh + (size_t)HC * B * H1;
  float* vsh = idh + (size_t)HC * B * H1;
  float* ish = vsh + (size_t)B * H1;
  float* vdo = ish + (size_t)B * H1;
  float* ido = vdo + B * OC * NOUT;
  float* vso = ido + B * OC * NOUT;
  float* iso = vso + B * NOUT;
  float* dyn = iso + B * NOUT;
  const int NSTATE = (int)(dyn - st);                              // 1,585,664

  size_t fixed_bytes = (size_t)((char*)dyn - ws);
  size_t avail = (ws_size > fixed_bytes + 256) ? ws_size - fixed_bytes - 256 : 0;
  const size_t per_t = (size_t)HC * B * H1 * 4 /*cur*/ +
                       (size_t)B * FS2 * 2 * 2 /*xh+xl*/;          // 4 MB
  int Tc = (int)(avail / per_t);
  if (Tc > T) Tc = T;
  if (Tc < 1) Tc = 1;

  float* cur = dyn;
  unsigned short* xh = (unsigned short*)(cur + (size_t)Tc * HC * B * H1);
  unsigned short* xl = xh + (size_t)Tc * B * FS2;

  init_state<<<(NSTATE + 255) / 256, 256, 0, stream>>>(st, NSTATE);
  conv_w<<<dim3(H1 / 64, NK / 64, HC), 256, 0, stream>>>(wh, wth, wtl);

  for (int t0 = 0; t0 < T; t0 += Tc) {
    int tc = (T - t0 < Tc) ? (T - t0) : Tc;
    int Mc = tc * B;
    int n4 = Mc * (FS2 / 4);
    int cb = (n4 + 255) / 256; if (cb > 2048) cb = 2048;
    conv_x<<<cb, 256, 0, stream>>>((const float4*)(x + (size_t)t0 * B * FS2),
                                   (ushort4*)xh, (ushort4*)xl, n4);
    gemm_split<<<dim3(H1 / 128, Mc / 128, HC), 256, 0, stream>>>(
        xh, xl, wth, wtl, cur, Mc);
    seq_chunk<<<B, 1024, 0, stream>>>(cur, wo, vdh, idh, vsh, ish,
                                      vdo, ido, vso, iso, out, t0, tc, Mc);
  }
}

// Round 3
// 540.995 us; speedup vs baseline: 4.0688x; 1.0132x over previous
//
#include <hip/hip_runtime.h>

#define B 128
#define HC 2
#define H1 2048
#define FS2 4096
#define NK 2048
#define OC 4
#define SPL2 512
#define NOUT 10
#define T 64
#define HBH (HC*B*H1)

typedef __attribute__((ext_vector_type(8))) short bf16x8;
typedef __attribute__((ext_vector_type(4))) float f32x4;

__device__ __forceinline__ unsigned short f2bf(float f) {
  unsigned u = __float_as_uint(f);
  u += 0x7fff + ((u >> 16) & 1);   // RNE
  return (unsigned short)(u >> 16);
}
__device__ __forceinline__ float bf2f(unsigned short s) {
  return __uint_as_float(((unsigned)s) << 16);
}

__device__ __forceinline__ void gload16(const void* g, void* l) {
  __builtin_amdgcn_global_load_lds(
      (const __attribute__((address_space(1))) unsigned int*)g,
      (__attribute__((address_space(3))) unsigned int*)l, 16, 0, 0);
}

__global__ __launch_bounds__(256) void init_state(float* __restrict__ p, int n) {
  int i = blockIdx.x * 256 + threadIdx.x;
  if (i < n) p[i] = 0.f;
}

// x fp32 -> hi/lo bf16
__global__ __launch_bounds__(256) void conv_x(
    const float4* __restrict__ xin, ushort4* __restrict__ xh,
    ushort4* __restrict__ xl, int n4) {
  for (int i = blockIdx.x * 256 + threadIdx.x; i < n4; i += gridDim.x * 256) {
    float4 v = xin[i];
    ushort4 h, lo;
    h.x = f2bf(v.x); h.y = f2bf(v.y); h.z = f2bf(v.z); h.w = f2bf(v.w);
    lo.x = f2bf(v.x - bf2f(h.x)); lo.y = f2bf(v.y - bf2f(h.y));
    lo.z = f2bf(v.z - bf2f(h.z)); lo.w = f2bf(v.w - bf2f(h.w));
    xh[i] = h; xl[i] = lo;
  }
}

// w_hidden [HC][K][N] fp32 -> wt hi/lo [HC][N][K] bf16 (transpose)
__global__ __launch_bounds__(256) void conv_w(
    const float* __restrict__ w, unsigned short* __restrict__ wth,
    unsigned short* __restrict__ wtl) {
  __shared__ float s[64][65];
  const int c = blockIdx.z;
  const int n0 = blockIdx.x * 64, k0 = blockIdx.y * 64;
  const int tid = threadIdx.x;
  const int r = tid >> 4, c4 = (tid & 15) * 4;
#pragma unroll
  for (int q = 0; q < 4; ++q) {
    int kr = r + q * 16;
    float4 v = *(const float4*)(w + ((size_t)c * NK + k0 + kr) * H1 + n0 + c4);
    s[kr][c4 + 0] = v.x; s[kr][c4 + 1] = v.y;
    s[kr][c4 + 2] = v.z; s[kr][c4 + 3] = v.w;
  }
  __syncthreads();
#pragma unroll
  for (int q = 0; q < 4; ++q) {
    int nr = r + q * 16;
    float a0 = s[c4 + 0][nr], a1 = s[c4 + 1][nr];
    float a2 = s[c4 + 2][nr], a3 = s[c4 + 3][nr];
    ushort4 h, lo;
    h.x = f2bf(a0); h.y = f2bf(a1); h.z = f2bf(a2); h.w = f2bf(a3);
    lo.x = f2bf(a0 - bf2f(h.x)); lo.y = f2bf(a1 - bf2f(h.y));
    lo.z = f2bf(a2 - bf2f(h.z)); lo.w = f2bf(a3 - bf2f(h.w));
    size_t off = ((size_t)c * H1 + n0 + nr) * NK + k0 + c4;
    *(ushort4*)(wth + off) = h;
    *(ushort4*)(wtl + off) = lo;
  }
}

// 256x256 double-buffered 2-phase split GEMM.
// LDS: 2 buf x {Ah,Al,Bh,Bl} x [256 rows][4 slots][8 bf16] = 128 KiB
__global__ __launch_bounds__(512, 2) void gemm_split(
    const unsigned short* __restrict__ xh, const unsigned short* __restrict__ xl,
    const unsigned short* __restrict__ wth, const unsigned short* __restrict__ wtl,
    float* __restrict__ cur, int Mc, int nMblk) {
  // bijective XCD swizzle; logical order (c, nb)-major, mb inner so each
  // XCD chunk shares 2 B-panels (~4MB, L2-resident)
  const int nwg = gridDim.x;
  const int q8 = nwg >> 3, r8 = nwg & 7;
  const int xcd = blockIdx.x & 7, idx8 = blockIdx.x >> 3;
  const int wg = (xcd < r8 ? xcd * (q8 + 1) : r8 * (q8 + 1) + (xcd - r8) * q8) + idx8;
  const int mb = wg % nMblk;
  const int rest = wg / nMblk;
  const int nb = rest & 7;
  const int c = rest >> 3;
  const int bm = mb * 256, bn = nb * 256;

  __shared__ unsigned short lds[65536];  // [buf][mat][8192]
  const int tid = threadIdx.x;

  // staging maps (linear LDS dest = lane x 16B; source pre-swizzled)
  unsigned dstOff[2]; size_t srcA[2], srcB[2];
#pragma unroll
  for (int q = 0; q < 2; ++q) {
    int idx = q * 512 + tid;
    int row = idx >> 2, ps = idx & 3;
    int ks = (ps - (row >> 1)) & 3;
    int ar = bm + row; if (ar > Mc - 1) ar = Mc - 1;
    srcA[q] = (size_t)ar * FS2 + (size_t)c * NK + ks * 8;
    srcB[q] = (size_t)c * NK * H1 + (size_t)(bn + row) * NK + ks * 8;
    dstOff[q] = idx * 8;
  }

  const int l = tid & 63, w = tid >> 6;
  const int wr = w >> 2, wc = w & 3;          // 2 x 4 waves, wave tile 128x64
  const int lrow = l & 15, lks = l >> 4;
  unsigned aoff[8], boff[4];
#pragma unroll
  for (int m = 0; m < 8; ++m) {
    int row = wr * 128 + m * 16 + lrow;
    int ps = (lks + (row >> 1)) & 3;
    aoff[m] = row * 32 + ps * 8;
  }
#pragma unroll
  for (int n = 0; n < 4; ++n) {
    int rn = wc * 64 + n * 16 + lrow;
    int ps = (lks + (rn >> 1)) & 3;
    boff[n] = rn * 32 + ps * 8;
  }

  f32x4 acc[8][4];
#pragma unroll
  for (int m = 0; m < 8; ++m)
#pragma unroll
    for (int n = 0; n < 4; ++n) acc[m][n] = (f32x4){0.f, 0.f, 0.f, 0.f};

  // prologue: stage K-tile 0 into buf 0
#pragma unroll
  for (int q = 0; q < 2; ++q) {
    gload16(xh + srcA[q], &lds[dstOff[q]]);
    gload16(xl + srcA[q], &lds[8192 + dstOff[q]]);
    gload16(wth + srcB[q], &lds[16384 + dstOff[q]]);
    gload16(wtl + srcB[q], &lds[24576 + dstOff[q]]);
  }
  __syncthreads();

  const int NT = NK / 32;
  int curb = 0;
  for (int kt = 0; kt < NT; ++kt) {
    if (kt + 1 < NT) {
      const int k0 = (kt + 1) * 32;
      const unsigned nb0 = (curb ^ 1) * 32768;
#pragma unroll
      for (int q = 0; q < 2; ++q) {
        gload16(xh + srcA[q] + k0, &lds[nb0 + dstOff[q]]);
        gload16(xl + srcA[q] + k0, &lds[nb0 + 8192 + dstOff[q]]);
        gload16(wth + srcB[q] + k0, &lds[nb0 + 16384 + dstOff[q]]);
        gload16(wtl + srcB[q] + k0, &lds[nb0 + 24576 + dstOff[q]]);
      }
    }
    const unsigned short* bc = &lds[curb * 32768];
    bf16x8 bh[4], bl[4];
#pragma unroll
    for (int n = 0; n < 4; ++n) {
      bh[n] = *(const bf16x8*)&bc[16384 + boff[n]];
      bl[n] = *(const bf16x8*)&bc[24576 + boff[n]];
    }
#pragma unroll
    for (int mh = 0; mh < 2; ++mh) {
      bf16x8 ah[4], al[4];
#pragma unroll
      for (int mm = 0; mm < 4; ++mm) {
        ah[mm] = *(const bf16x8*)&bc[aoff[mh * 4 + mm]];
        al[mm] = *(const bf16x8*)&bc[8192 + aoff[mh * 4 + mm]];
      }
#pragma unroll
      for (int mm = 0; mm < 4; ++mm)
#pragma unroll
        for (int n = 0; n < 4; ++n) {
          int m = mh * 4 + mm;
          acc[m][n] = __builtin_amdgcn_mfma_f32_16x16x32_bf16(ah[mm], bh[n], acc[m][n], 0, 0, 0);
          acc[m][n] = __builtin_amdgcn_mfma_f32_16x16x32_bf16(ah[mm], bl[n], acc[m][n], 0, 0, 0);
          acc[m][n] = __builtin_amdgcn_mfma_f32_16x16x32_bf16(al[mm], bh[n], acc[m][n], 0, 0, 0);
        }
    }
    __syncthreads();
    curb ^= 1;
  }

  float* Cc = cur + (size_t)c * Mc * H1;
#pragma unroll
  for (int m = 0; m < 8; ++m) {
    int grow = bm + wr * 128 + m * 16 + (l >> 4) * 4;
    if (grow < Mc) {
#pragma unroll
      for (int n = 0; n < 4; ++n) {
        int gcol = bn + wc * 64 + n * 16 + (l & 15);
        float* Cp = Cc + (size_t)grow * H1 + gcol;
        Cp[0]      = acc[m][n][0];
        Cp[H1]     = acc[m][n][1];
        Cp[2 * H1] = acc[m][n][2];
        Cp[3 * H1] = acc[m][n][3];
      }
    }
  }
}

// sequential dynamics: one block per (b, oc); defers readout via sp_g spikes
__global__ __launch_bounds__(256) void seq_chunk(
    const float* __restrict__ cur, const float* __restrict__ wout,
    float* __restrict__ vdh, float* __restrict__ idh,
    float* __restrict__ vsh, float* __restrict__ ish,
    float* __restrict__ vdo, float* __restrict__ ido,
    float* __restrict__ sp_g, int t0, int tc, int Mc) {
  const int b = blockIdx.x >> 2;
  const int oc = blockIdx.x & 3;
  const int tid = threadIdx.x;
  __shared__ float wols[SPL2 * NOUT];  // 20KB
  __shared__ float zls[SPL2];
  __shared__ float cols[16];

#pragma unroll
  for (int q = 0; q < 5; ++q) {
    int i4 = q * 256 + tid;
    ((float4*)wols)[i4] = ((const float4*)(wout + (size_t)oc * SPL2 * NOUT))[i4];
  }
  const int hb = oc * SPL2;
  float vdl[HC][2], idl[HC][2], vsl[2], isl[2];
#pragma unroll
  for (int c = 0; c < HC; ++c)
#pragma unroll
    for (int u = 0; u < 2; ++u) {
      size_t o = ((size_t)c * B + b) * H1 + hb + tid + u * 256;
      vdl[c][u] = vdh[o]; idl[c][u] = idh[o];
    }
#pragma unroll
  for (int u = 0; u < 2; ++u) {
    size_t o = (size_t)b * H1 + hb + tid + u * 256;
    vsl[u] = vsh[o]; isl[u] = ish[o];
  }
  float vo = 0.f, io = 0.f;
  if (tid < NOUT) {
    vo = vdo[(oc * B + b) * NOUT + tid];
    io = ido[(oc * B + b) * NOUT + tid];
  }
  float pc[HC][2];
#pragma unroll
  for (int c = 0; c < HC; ++c)
#pragma unroll
    for (int u = 0; u < 2; ++u)
      pc[c][u] = cur[((size_t)c * Mc + b) * H1 + hb + tid + u * 256];

  for (int tl = 0; tl < tc; ++tl) {
#pragma unroll
    for (int u = 0; u < 2; ++u) {
      float zsum = 0.f;
#pragma unroll
      for (int c = 0; c < HC; ++c) {
        float v = vdl[c][u], i = idl[c][u];
        float vdec = v + 0.1f * (i - v);
        float idec = 0.8f * i;
        bool z = (vdec - 1.0f) > 0.f;
        vdl[c][u] = z ? 0.f : vdec;
        idl[c][u] = idec + pc[c][u];
        zsum += z ? 1.f : 0.f;
      }
      float v = vsl[u], i = isl[u];
      float vdec = v + 0.1f * (i - v);
      float idec = 0.8f * i;
      bool z = (vdec - 1.0f) > 0.f;
      vsl[u] = z ? 0.f : vdec;
      isl[u] = idec + zsum;
      zls[tid + u * 256] = z ? 1.f : 0.f;
    }
    if (tl + 1 < tc) {
#pragma unroll
      for (int c = 0; c < HC; ++c)
#pragma unroll
        for (int u = 0; u < 2; ++u)
          pc[c][u] = cur[((size_t)c * Mc + (tl + 1) * B + b) * H1 + hb + tid + u * 256];
    }
    __syncthreads();
    {
      const int g = tid >> 4, li = tid & 15;
      if (g < NOUT) {
        float s = 0.f;
#pragma unroll
        for (int j = 0; j < 32; ++j) {
          int i2 = li + 16 * j;
          s += zls[i2] * wols[i2 * NOUT + g];
        }
        s += __shfl_xor(s, 1); s += __shfl_xor(s, 2);
        s += __shfl_xor(s, 4); s += __shfl_xor(s, 8);
        if (li == 0) cols[g] = s;
      }
    }
    __syncthreads();
    if (tid < NOUT) {
      float vdec = vo + 0.1f * (io - vo);
      float idec = 0.8f * io;
      bool z = (vdec - 1.0f) > 0.f;
      vo = z ? 0.f : vdec;
      io = idec + cols[tid];
      sp_g[((size_t)(t0 + tl) * B + b) * (OC * NOUT) + oc * NOUT + tid] = z ? 1.f : 0.f;
    }
  }

#pragma unroll
  for (int c = 0; c < HC; ++c)
#pragma unroll
    for (int u = 0; u < 2; ++u) {
      size_t o = ((size_t)c * B + b) * H1 + hb + tid + u * 256;
      vdh[o] = vdl[c][u]; idh[o] = idl[c][u];
    }
#pragma unroll
  for (int u = 0; u < 2; ++u) {
    size_t o = (size_t)b * H1 + hb + tid + u * 256;
    vsh[o] = vsl[u]; ish[o] = isl[u];
  }
  if (tid < NOUT) {
    vdo[(oc * B + b) * NOUT + tid] = vo;
    ido[(oc * B + b) * NOUT + tid] = io;
  }
}

// final readout integration over stored output spikes
__global__ __launch_bounds__(256) void integrate_out(
    const float* __restrict__ sp_g, float* __restrict__ out) {
  int i = blockIdx.x * 256 + threadIdx.x;
  if (i >= B * NOUT) return;
  int b = i / NOUT, o = i % NOUT;
  float vr = 0.f, ir = 0.f;
  for (int t = 0; t < T; ++t) {
    const float* p = sp_g + ((size_t)(t * B + b) * OC) * NOUT + o;
    float ssum = ((p[0] + p[NOUT]) + p[2 * NOUT]) + p[3 * NOUT];
    float vn = vr + 0.1f * (ir - vr);
    ir = 0.8f * ir + ssum;
    vr = vn;
    out[(size_t)(t * B + b) * NOUT + o] = vn;
  }
}

extern "C" void kernel_launch(void* const* d_in, const int* in_sizes, int n_in,
                              void* d_out, int out_size, void* d_ws, size_t ws_size,
                              hipStream_t stream) {
  const float* x  = (const float*)d_in[0];
  const float* wh = (const float*)d_in[1];
  const float* wo = (const float*)d_in[2];
  float* out = (float*)d_out;
  char* ws = (char*)d_ws;

  unsigned short* wth = (unsigned short*)ws;
  unsigned short* wtl = wth + (size_t)HC * NK * H1;
  float* st  = (float*)(wtl + (size_t)HC * NK * H1);
  float* vdh = st;
  float* idh = vdh + HBH;
  float* vsh = idh + HBH;
  float* ish = vsh + (size_t)B * H1;
  float* vdo = ish + (size_t)B * H1;
  float* ido = vdo + OC * B * NOUT;
  float* sp_g = ido + OC * B * NOUT;
  float* dyn = sp_g + (size_t)T * B * OC * NOUT;
  const int NSTATE = (int)(sp_g - st);

  size_t fixed_bytes = (size_t)((char*)dyn - ws);
  size_t avail = (ws_size > fixed_bytes + 256) ? ws_size - fixed_bytes - 256 : 0;
  const size_t per_t = (size_t)HC * B * H1 * 4 + (size_t)B * FS2 * 2 * 2;  // 4MB
  int Tc = (int)(avail / per_t);
  if (Tc > T) Tc = T;
  if (Tc >= 2) Tc &= ~1;
  if (Tc < 1) Tc = 1;

  float* cur = dyn;
  unsigned short* xh = (unsigned short*)(cur + (size_t)Tc * HC * B * H1);
  unsigned short* xl = xh + (size_t)Tc * B * FS2;

  init_state<<<(NSTATE + 255) / 256, 256, 0, stream>>>(st, NSTATE);
  conv_w<<<dim3(H1 / 64, NK / 64, HC), 256, 0, stream>>>(wh, wth, wtl);

  for (int t0 = 0; t0 < T; t0 += Tc) {
    int tc = (T - t0 < Tc) ? (T - t0) : Tc;
    int Mc = tc * B;
    int n4 = Mc * (FS2 / 4);
    int cb = (n4 + 255) / 256; if (cb > 2048) cb = 2048;
    conv_x<<<cb, 256, 0, stream>>>((const float4*)(x + (size_t)t0 * B * FS2),
                                   (ushort4*)xh, (ushort4*)xl, n4);
    int nMblk = (Mc + 255) / 256;
    gemm_split<<<HC * 8 * nMblk, 512, 0, stream>>>(xh, xl, wth, wtl, cur, Mc, nMblk);
    seq_chunk<<<B * OC, 256, 0, stream>>>(cur, wo, vdh, idh, vsh, ish,
                                          vdo, ido, sp_g, t0, tc, Mc);
  }
  integrate_out<<<(B * NOUT + 255) / 256, 256, 0, stream>>>(sp_g, out);
}